// Round 3
// baseline (261.792 us; speedup 1.0000x reference)
//
#include <hip/hip_runtime.h>

#define NROW 8192
#define INF  512
#define OUTF 256
#define M_ELEM (NROW * OUTF)   // 2,097,152 f32 per output matrix

typedef __bf16 v8bf __attribute__((ext_vector_type(8)));
typedef __bf16 v4bf __attribute__((ext_vector_type(4)));
typedef float  v4f  __attribute__((ext_vector_type(4)));

__device__ __forceinline__ v8bf cvt_bf8(v4f u0, v4f u1) {
  v8bf v;
  v[0]=(__bf16)u0[0]; v[1]=(__bf16)u0[1]; v[2]=(__bf16)u0[2]; v[3]=(__bf16)u0[3];
  v[4]=(__bf16)u1[0]; v[5]=(__bf16)u1[1]; v[6]=(__bf16)u1[2]; v[7]=(__bf16)u1[3];
  return v;
}

// ---------------------------------------------------------------------------
// Kernel A: seq = feat @ W^T, bf16 MFMA, output in B-fragment-packed layout:
//   elem(m,o) -> (((m>>5)*16 + (o>>4))*64 + ((m>>3)&3)*16 + (o&15))*8 + (m&7)
// ---------------------------------------------------------------------------
__global__ __launch_bounds__(256) void seq_fts_kernel(
    const float* __restrict__ feat, const float* __restrict__ W,
    __bf16* __restrict__ Bp) {
  const int tid  = threadIdx.x;
  const int lane = tid & 63, w = tid >> 6;
  const int llo  = lane & 15, lhi = lane >> 4;
  const int row0 = blockIdx.x * 64;
  const int col0 = w * 64;

  v4f acc[4][4] = {};
#pragma unroll 1
  for (int kb = 0; kb < INF / 32; ++kb) {
    const int kofs = kb * 32 + lhi * 8;
    v8bf a[4], b[4];
#pragma unroll
    for (int i = 0; i < 4; ++i) {
      const float* p = feat + (size_t)(row0 + i * 16 + llo) * INF + kofs;
      a[i] = cvt_bf8(*(const v4f*)p, *(const v4f*)(p + 4));
    }
#pragma unroll
    for (int i = 0; i < 4; ++i) {
      const float* p = W + (size_t)(col0 + i * 16 + llo) * INF + kofs;
      b[i] = cvt_bf8(*(const v4f*)p, *(const v4f*)(p + 4));
    }
#pragma unroll
    for (int ri = 0; ri < 4; ++ri)
#pragma unroll
      for (int ci = 0; ci < 4; ++ci)
        acc[ri][ci] = __builtin_amdgcn_mfma_f32_16x16x32_bf16(
            a[ri], b[ci], acc[ri][ci], 0, 0, 0);
  }
#pragma unroll
  for (int ri = 0; ri < 4; ++ri)
#pragma unroll
    for (int ci = 0; ci < 4; ++ci) {
      const int mf = row0 + ri * 16 + lhi * 4;
      const int o  = col0 + ci * 16 + llo;
      size_t e = (((size_t)(mf >> 5) * 16 + (o >> 4)) * 64 +
                  ((mf >> 3) & 3) * 16 + (o & 15)) * 8 + (mf & 7);
      v4bf v;
      v[0] = (__bf16)acc[ri][ci][0]; v[1] = (__bf16)acc[ri][ci][1];
      v[2] = (__bf16)acc[ri][ci][2]; v[3] = (__bf16)acc[ri][ci][3];
      *(v4bf*)(Bp + e) = v;
    }
}

// ---------------------------------------------------------------------------
// Kernel B: partial[z,y] = adj_z[rows, kslice] @ seq   (raw f32 sums)
// BM=128, 8 waves (2x4), K-split across blockIdx.y. A-tile 128x64 f32 in
// double-buffered, XOR-swizzled LDS (64 KB -> 2 blocks/CU). B single-buffered
// in regs, issued BEFORE the A-stage (FIFO: B waits never drain A prefetch).
// ---------------------------------------------------------------------------
__global__ __launch_bounds__(512, 4) void gcn_agg_kernel(
    const float* __restrict__ adjA, const float* __restrict__ adjB,
    const __bf16* __restrict__ Bp, float* __restrict__ P,
    int S, int nsteps) {
  const int tid  = threadIdx.x;
  const int lane = tid & 63, w = tid >> 6;
  const int llo  = lane & 15, lhi = lane >> 4;
  const int wr   = w >> 2, wc = w & 3;       // wave grid 2x4, tile 64x64
  const int row0 = blockIdx.x * 128;
  const int z    = blockIdx.z;
  const float* __restrict__ adj = z ? adjB : adjA;
  const int k0   = blockIdx.y * nsteps * 64;
  const int kk0  = blockIdx.y * nsteps * 2;

  __shared__ float Abuf[2][128 * 64];        // 64 KB

  v4f acc[4][4] = {};

  // wave w stages tile-local rows [w*16, w*16+16): 4 x global_load_lds(16B)
  auto stage = [&](int buf, int kb) {
#pragma unroll
    for (int i = 0; i < 4; ++i) {
      const int row = w * 16 + i * 4 + lhi;
      const int k4  = llo ^ (i * 4 + lhi);   // pre-swizzled source slot
      const float* src = adj + (size_t)(row0 + row) * NROW + k0 + kb * 64 + k4 * 4;
      char* lds = (char*)(&Abuf[buf][0]) + (size_t)(w * 16 + i * 4) * 256;
      __builtin_amdgcn_global_load_lds(
          (const __attribute__((address_space(1))) void*)src,
          (__attribute__((address_space(3))) void*)lds, 16, 0, 0);
    }
  };

  auto read_a = [&](int buf, int ri, int s) -> v8bf {
    const int row  = wr * 64 + ri * 16 + llo;        // row & 15 == llo
    const int k4a  = s * 8 + lhi * 2;
    const char* base = (const char*)(&Abuf[buf][0]) + (size_t)row * 256;
    v4f u0 = *(const v4f*)(base + (((k4a    ) ^ llo) << 4));
    v4f u1 = *(const v4f*)(base + (((k4a + 1) ^ llo) << 4));
    return cvt_bf8(u0, u1);
  };

  const __bf16* __restrict__ Bpw = Bp + ((size_t)(wc * 4) * 64 + lane) * 8;

  stage(0, 0);

#pragma unroll 1
  for (int kb = 0; kb < nsteps; ++kb) {
    const int cur = kb & 1;
    asm volatile("s_waitcnt vmcnt(0) lgkmcnt(0)" ::: "memory");
    __builtin_amdgcn_s_barrier();
    __builtin_amdgcn_sched_barrier(0);
    // B regs for this K-step: 8 x dwordx4 from packed Bp (L2/LLC). Issue
    // BEFORE the next A-stage so MFMA's B-waits (vmcnt 8/4) never drain it.
    v8bf b[8];
    {
      const int kk = kk0 + kb * 2;
#pragma unroll
      for (int s = 0; s < 2; ++s)
#pragma unroll
        for (int ci = 0; ci < 4; ++ci)
          b[s * 4 + ci] =
              *(const v8bf*)(Bpw + ((size_t)((kk + s) * 16 + ci)) * 512);
    }
    __builtin_amdgcn_sched_barrier(0);
    if (kb + 1 < nsteps) stage(cur ^ 1, kb + 1);
    __builtin_amdgcn_sched_barrier(0);
#pragma unroll
    for (int s = 0; s < 2; ++s) {
      v8bf a[4];
#pragma unroll
      for (int ri = 0; ri < 4; ++ri) a[ri] = read_a(cur, ri, s);
#pragma unroll
      for (int ci = 0; ci < 4; ++ci)
#pragma unroll
        for (int ri = 0; ri < 4; ++ri)
          acc[ri][ci] = __builtin_amdgcn_mfma_f32_16x16x32_bf16(
              a[ri], b[s * 4 + ci], acc[ri][ci], 0, 0, 0);
    }
  }

  // raw partial sums (bias/prelu in the reduce epilogue)
  float* __restrict__ Pp = P + (size_t)(z * S + blockIdx.y) * M_ELEM;
#pragma unroll
  for (int ci = 0; ci < 4; ++ci) {
    const int o = wc * 64 + ci * 16 + llo;
#pragma unroll
    for (int ri = 0; ri < 4; ++ri) {
      const int m = row0 + wr * 64 + ri * 16 + lhi * 4;
#pragma unroll
      for (int r = 0; r < 4; ++r)
        Pp[(size_t)(m + r) * OUTF + o] = acc[ri][ci][r];
    }
  }
}

// ---------------------------------------------------------------------------
// Epilogue: out = prelu(sum_y partial[z,y] + bias). v4f, grid-stride.
// For S==1, P == out (in-place bias+prelu).
// ---------------------------------------------------------------------------
__global__ __launch_bounds__(256) void reduce_kernel(
    const float* __restrict__ P, const float* __restrict__ bias,
    const float* __restrict__ prelu_a, float* __restrict__ out, int S) {
  const float slope = prelu_a[0];
  const int nv4 = 2 * M_ELEM / 4;
  for (int v = blockIdx.x * 256 + threadIdx.x; v < nv4; v += gridDim.x * 256) {
    const int z = v >> 19;                       // 524288 v4 per matrix
    const size_t r = (size_t)(v & 524287) * 4;
    const int o = (int)(r & 255);
    v4f s = {};
    for (int y = 0; y < S; ++y)
      s += *(const v4f*)(P + (size_t)(z * S + y) * M_ELEM + r);
    v4f b4 = *(const v4f*)(bias + o);
    s += b4;
    v4f res;
#pragma unroll
    for (int i = 0; i < 4; ++i) res[i] = s[i] >= 0.f ? s[i] : slope * s[i];
    *(v4f*)(out + (size_t)z * M_ELEM + r) = res;
  }
}

extern "C" void kernel_launch(void* const* d_in, const int* in_sizes, int n_in,
                              void* d_out, int out_size, void* d_ws, size_t ws_size,
                              hipStream_t stream) {
  const float* feat = (const float*)d_in[0];
  const float* adj  = (const float*)d_in[1];
  const float* aug  = (const float*)d_in[2];
  const float* W    = (const float*)d_in[3];
  const float* bias = (const float*)d_in[4];
  const float* pa   = (const float*)d_in[5];
  float* out = (float*)d_out;
  __bf16* Bp = (__bf16*)d_ws;                    // 4 MB packed seq_fts

  const size_t MB = 1ull << 20;
  int S;
  if      (ws_size >= 4 * MB + 4 * 2 * (size_t)M_ELEM * 4) S = 4;  // 68 MB
  else if (ws_size >= 4 * MB + 2 * 2 * (size_t)M_ELEM * 4) S = 2;  // 36 MB
  else S = 1;
  float* P = (S == 1) ? out : (float*)((char*)d_ws + 4 * MB);
  const int nsteps = NROW / 64 / S;

  seq_fts_kernel<<<dim3(NROW / 64), 256, 0, stream>>>(feat, W, Bp);
  gcn_agg_kernel<<<dim3(NROW / 128, S, 2), 512, 0, stream>>>(
      adj, aug, Bp, P, S, nsteps);
  reduce_kernel<<<dim3(1024), 256, 0, stream>>>(P, bias, pa, out, S);
}

// Round 4
// 236.117 us; speedup vs baseline: 1.1087x; 1.1087x over previous
//
#include <hip/hip_runtime.h>

#define NROW 8192
#define INF  512
#define OUTF 256
#define M_ELEM (NROW * OUTF)   // 2,097,152 f32 per output matrix

typedef __bf16 v8bf __attribute__((ext_vector_type(8)));
typedef __bf16 v4bf __attribute__((ext_vector_type(4)));
typedef float  v4f  __attribute__((ext_vector_type(4)));

__device__ __forceinline__ v8bf cvt_bf8(v4f u0, v4f u1) {
  v8bf v;
  v[0]=(__bf16)u0[0]; v[1]=(__bf16)u0[1]; v[2]=(__bf16)u0[2]; v[3]=(__bf16)u0[3];
  v[4]=(__bf16)u1[0]; v[5]=(__bf16)u1[1]; v[6]=(__bf16)u1[2]; v[7]=(__bf16)u1[3];
  return v;
}

// ---------------------------------------------------------------------------
// Kernel A: seq = feat @ W^T, bf16 MFMA, output in B-fragment-packed layout:
//   elem(m,o) -> (((m>>5)*16 + (o>>4))*64 + ((m>>3)&3)*16 + (o&15))*8 + (m&7)
// i.e. 1KB chunks indexed by (kk = m>>5, cig = o>>4), lane-contiguous inside.
// ---------------------------------------------------------------------------
__global__ __launch_bounds__(256) void seq_fts_kernel(
    const float* __restrict__ feat, const float* __restrict__ W,
    __bf16* __restrict__ Bp) {
  const int tid  = threadIdx.x;
  const int lane = tid & 63, w = tid >> 6;
  const int llo  = lane & 15, lhi = lane >> 4;
  const int row0 = blockIdx.x * 64;
  const int col0 = w * 64;

  v4f acc[4][4] = {};
#pragma unroll 1
  for (int kb = 0; kb < INF / 32; ++kb) {
    const int kofs = kb * 32 + lhi * 8;
    v8bf a[4], b[4];
#pragma unroll
    for (int i = 0; i < 4; ++i) {
      const float* p = feat + (size_t)(row0 + i * 16 + llo) * INF + kofs;
      a[i] = cvt_bf8(*(const v4f*)p, *(const v4f*)(p + 4));
    }
#pragma unroll
    for (int i = 0; i < 4; ++i) {
      const float* p = W + (size_t)(col0 + i * 16 + llo) * INF + kofs;
      b[i] = cvt_bf8(*(const v4f*)p, *(const v4f*)(p + 4));
    }
#pragma unroll
    for (int ri = 0; ri < 4; ++ri)
#pragma unroll
      for (int ci = 0; ci < 4; ++ci)
        acc[ri][ci] = __builtin_amdgcn_mfma_f32_16x16x32_bf16(
            a[ri], b[ci], acc[ri][ci], 0, 0, 0);
  }
#pragma unroll
  for (int ri = 0; ri < 4; ++ri)
#pragma unroll
    for (int ci = 0; ci < 4; ++ci) {
      const int mf = row0 + ri * 16 + lhi * 4;
      const int o  = col0 + ci * 16 + llo;
      size_t e = (((size_t)(mf >> 5) * 16 + (o >> 4)) * 64 +
                  ((mf >> 3) & 3) * 16 + (o & 15)) * 8 + (mf & 7);
      v4bf v;
      v[0] = (__bf16)acc[ri][ci][0]; v[1] = (__bf16)acc[ri][ci][1];
      v[2] = (__bf16)acc[ri][ci][2]; v[3] = (__bf16)acc[ri][ci][3];
      *(v4bf*)(Bp + e) = v;
    }
}

// ---------------------------------------------------------------------------
// Kernel B: partial[z,y] = adj_z[rows, kslice] @ seq
// FLIPPED staging: adj (HBM stream) -> registers, double-buffered per wave,
// compiler-counted vmcnt, no barrier coupling. seq tile (32 KB, LLC-hot) ->
// LDS via global_load_lds, double-buffered; the ONLY manual wait is
// vmcnt(8) for the B tile (leaves next A-reg loads in flight).
// Block: 8 waves = 4 row-groups x 2 col-halves; wave = 32 rows x 128 cols.
// ---------------------------------------------------------------------------
__global__ __launch_bounds__(512, 2) void gcn_agg_kernel(
    const float* __restrict__ adjA, const float* __restrict__ adjB,
    const __bf16* __restrict__ Bp, float* __restrict__ P,
    int S, int nsteps) {
  const int tid  = threadIdx.x;
  const int lane = tid & 63, w = tid >> 6;
  const int llo  = lane & 15, lhi = lane >> 4;
  const int wrow = w >> 1, wcol = w & 1;
  const int row0 = blockIdx.x * 128;
  const int z    = blockIdx.z;
  const float* __restrict__ adj = z ? adjB : adjA;
  const int k0   = blockIdx.y * nsteps * 64;   // float index
  const int kk0  = blockIdx.y * nsteps * 2;    // 32-k chunk index

  __shared__ __align__(16) char Blds[2][32768];

  v4f acc[2][8] = {};

  // --- A: adj -> regs. Per K-step: 8 x dwordx4 per lane (2ri x 2s x 2j).
  const float* abase =
      adj + (size_t)(row0 + wrow * 32 + llo) * NROW + k0 + lhi * 8;
  auto load_a = [&](int kb, v4f (&ar)[8]) {
    const float* pk = abase + kb * 64;
#pragma unroll
    for (int ri = 0; ri < 2; ++ri)
#pragma unroll
      for (int s = 0; s < 2; ++s) {
        const float* p = pk + (size_t)ri * 16 * NROW + s * 32;
        ar[(ri * 2 + s) * 2 + 0] = *(const v4f*)p;
        ar[(ri * 2 + s) * 2 + 1] = *(const v4f*)(p + 4);
      }
  };

  // --- B: 32 KB contiguous Bp chunk -> LDS (linear copy; layout preserved).
  auto stage_b = [&](int buf, int kb) {
    const char* src = (const char*)Bp +
        ((size_t)(kk0 + kb * 2) * 16384 + w * 4096 + lane * 16);
    char* dst = &Blds[buf][w * 4096];
#pragma unroll
    for (int i = 0; i < 4; ++i)
      __builtin_amdgcn_global_load_lds(
          (const __attribute__((address_space(1))) void*)(src + i * 1024),
          (__attribute__((address_space(3))) void*)(dst + i * 1024), 16, 0, 0);
  };

  auto compute = [&](int buf, v4f (&ar)[8]) {
    v8bf af[2][2];
#pragma unroll
    for (int ri = 0; ri < 2; ++ri)
#pragma unroll
      for (int s = 0; s < 2; ++s)
        af[ri][s] = cvt_bf8(ar[(ri * 2 + s) * 2], ar[(ri * 2 + s) * 2 + 1]);
    const char* bb = &Blds[buf][wcol * 8 * 1024 + lane * 16];
#pragma unroll
    for (int s = 0; s < 2; ++s)
#pragma unroll
      for (int ci = 0; ci < 8; ++ci) {
        v8bf bf = *(const v8bf*)(bb + (s * 16 + ci) * 1024);
#pragma unroll
        for (int ri = 0; ri < 2; ++ri)
          acc[ri][ci] = __builtin_amdgcn_mfma_f32_16x16x32_bf16(
              af[ri][s], bf, acc[ri][ci], 0, 0, 0);
      }
  };

  v4f ar0[8], ar1[8];
  stage_b(0, 0);        // FIFO: [B(0) x4, A(0) x8]
  load_a(0, ar0);

#pragma unroll 1
  for (int kb = 0; kb < nsteps; kb += 2) {
    // ---- even: consume buf0/ar0, prefetch kb+1 into buf1/ar1
    asm volatile("s_waitcnt vmcnt(8)" ::: "memory");  // B(kb) landed; A(kb) older -> also done
    __builtin_amdgcn_s_barrier();
    __builtin_amdgcn_sched_barrier(0);
    {
      const int kn = (kb + 1 < nsteps) ? kb + 1 : nsteps - 1;
      stage_b(1, kn);
      load_a(kn, ar1);
    }
    compute(0, ar0);
    // ---- odd: consume buf1/ar1, prefetch kb+2 into buf0/ar0
    asm volatile("s_waitcnt vmcnt(8)" ::: "memory");
    __builtin_amdgcn_s_barrier();
    __builtin_amdgcn_sched_barrier(0);
    {
      const int kn = (kb + 2 < nsteps) ? kb + 2 : nsteps - 1;
      stage_b(0, kn);
      load_a(kn, ar0);
    }
    compute(1, ar1);
  }

  // raw partial sums (bias/prelu in the reduce epilogue)
  float* __restrict__ Pp = P + (size_t)(z * S + blockIdx.y) * M_ELEM;
#pragma unroll
  for (int ci = 0; ci < 8; ++ci) {
    const int o = wcol * 128 + ci * 16 + llo;
#pragma unroll
    for (int ri = 0; ri < 2; ++ri) {
      const int m = row0 + wrow * 32 + ri * 16 + lhi * 4;
#pragma unroll
      for (int r = 0; r < 4; ++r)
        Pp[(size_t)(m + r) * OUTF + o] = acc[ri][ci][r];
    }
  }
}

// ---------------------------------------------------------------------------
// Epilogue: out = prelu(sum_y partial[z,y] + bias). v4f, grid-stride.
// For S==1, P == out (in-place bias+prelu).
// ---------------------------------------------------------------------------
__global__ __launch_bounds__(256) void reduce_kernel(
    const float* __restrict__ P, const float* __restrict__ bias,
    const float* __restrict__ prelu_a, float* __restrict__ out, int S) {
  const float slope = prelu_a[0];
  const int nv4 = 2 * M_ELEM / 4;
  for (int v = blockIdx.x * 256 + threadIdx.x; v < nv4; v += gridDim.x * 256) {
    const int z = v >> 19;                       // 524288 v4 per matrix
    const size_t r = (size_t)(v & 524287) * 4;
    const int o = (int)(r & 255);
    v4f s = {};
    for (int y = 0; y < S; ++y)
      s += *(const v4f*)(P + (size_t)(z * S + y) * M_ELEM + r);
    v4f b4 = *(const v4f*)(bias + o);
    s += b4;
    v4f res;
#pragma unroll
    for (int i = 0; i < 4; ++i) res[i] = s[i] >= 0.f ? s[i] : slope * s[i];
    *(v4f*)(out + (size_t)z * M_ELEM + r) = res;
  }
}

extern "C" void kernel_launch(void* const* d_in, const int* in_sizes, int n_in,
                              void* d_out, int out_size, void* d_ws, size_t ws_size,
                              hipStream_t stream) {
  const float* feat = (const float*)d_in[0];
  const float* adj  = (const float*)d_in[1];
  const float* aug  = (const float*)d_in[2];
  const float* W    = (const float*)d_in[3];
  const float* bias = (const float*)d_in[4];
  const float* pa   = (const float*)d_in[5];
  float* out = (float*)d_out;
  __bf16* Bp = (__bf16*)d_ws;                    // 4 MB packed seq_fts

  const size_t MB = 1ull << 20;
  int S = (ws_size >= 4 * MB + 2 * 2 * (size_t)M_ELEM * 4) ? 2 : 1;  // 36 MB
  float* P = (S == 1) ? out : (float*)((char*)d_ws + 4 * MB);
  const int nsteps = NROW / 64 / S;

  seq_fts_kernel<<<dim3(NROW / 64), 256, 0, stream>>>(feat, W, Bp);
  gcn_agg_kernel<<<dim3(NROW / 128, S, 2), 512, 0, stream>>>(
      adj, aug, Bp, P, S, nsteps);
  reduce_kernel<<<dim3(1024), 256, 0, stream>>>(P, bias, pa, out, S);
}